// Round 7
// baseline (897.051 us; speedup 1.0000x reference)
//
#include <hip/hip_runtime.h>
#include <hip/hip_cooperative_groups.h>
namespace cg = cooperative_groups;

// DigitCaps dynamic routing, B=256 R=192 C=96 O=16 I=20. fp32 in/out.
// u_hat never materialized. R7: TWO dispatches:
//   prep (classic): W->WtT bf16 k-major; X->Xk + xT; bij=0 (c-major)
//   routing_coop (cooperative, grid 720 x 256, 7 grid.sync()):
//     [gemm1 -> sync -> redsq -> sync -> gemm2 -> sync] x3 (last iter stops
//     after redsq). Phase bodies = R5 kernels VERBATIM (forced-inline);
//     arithmetic bit-identical to the 149.09us R5 build.
//   Fallback: if hipLaunchCooperativeKernel errors (capture unsupported),
//     launch the classic 9-dispatch R5 path.
// Rationale: kernel-time arithmetic sums to ~40us; measured 149us => ~12us
// per dispatch boundary. Coop sync fences at QUIESCED points (bounded
// phase-boundary refill from L3) unlike R1's in-flight per-block fences
// (continuous L2 thrash at HBM latency).
// Lessons: R1 fence storm; R2/R3 full-K = 2x traffic; R4 staging chunk
// order must keep 4-chunks = one row; R5 sigma-swz neutral (kept, free);
// R6 redsq/gemm2 "vectorization" regressed (reverted).

#define R_ 192
#define C_ 96
#define O_ 16
#define I_ 20
#define B_ 256
#define K1 3840   // R*I
#define N_ 1536   // C*O
#define ZSPLIT 15
#define KCH 256       // K1/ZSPLIT; 4 iters of BK=64 (2x BK32 sub-tiles)
#define STILE 393216  // N_*B_ elements per z-slice

typedef unsigned short u16;
typedef __attribute__((ext_vector_type(8))) short short8;
typedef __attribute__((ext_vector_type(4))) float floatx4;

__device__ inline float bf2f(u16 h) {
  union { unsigned int u; float f; } x; x.u = ((unsigned int)h) << 16; return x.f;
}
__device__ inline u16 f2bf(float f) {
  union { float f; unsigned int u; } x; x.f = f;
  unsigned int r = x.u + 0x7FFFu + ((x.u >> 16) & 1u);
  return (u16)(r >> 16);
}
__device__ inline unsigned int pack2(float a, float b) {
  return (unsigned int)f2bf(a) | ((unsigned int)f2bf(b) << 16);
}
// async 16B/lane global->LDS; lds base wave-uniform (lane scatters +16B)
__device__ inline void async16(const u16* g, u16* l) {
  __builtin_amdgcn_global_load_lds(
      (__attribute__((address_space(1))) void*)(unsigned long long)g,
      (__attribute__((address_space(3))) void*)(unsigned int)(unsigned long long)l,
      16, 0, 0);
}

// ---- shared-memory union for the fused kernel (52,224 B; 3 blocks/CU)
struct SmemG1 {
  u16 As[2][8192];   // 32 KB (sigma-swz)
  u16 Bs[2][4096];   // 16 KB (sigma-swz)
  float sm[4][192];  // 3 KB
};
struct SmemG2 {
  u16 As[2][8192];
  u16 Bs[2][4096];
};
struct SmemRS {
  float nsq_l[4][64];
};
union Smem {
  SmemG1 g1;
  SmemG2 g2;
  SmemRS rs;
};

// ---- fused prep: WtT gather (5760 blocks, 4 elems/thr); X cast+transpose
// (240); bij=0 c-major (18)
__global__ void k_prep(const float* __restrict__ W, const float* __restrict__ X,
                       u16* __restrict__ WtT, u16* __restrict__ Xk,
                       u16* __restrict__ xT, float* __restrict__ bij) {
  int bid = blockIdx.x;
  if (bid < 5760) {
    int t = (bid * 256 + threadIdx.x) << 2;    // 4-group stays in one n
    int n = t / K1, k = t - n * K1;
    int c = n >> 4, o = n & 15;
    const float* Wn = W + (size_t)(c * O_ + o) * I_;
    u16 h[4];
    #pragma unroll
    for (int e = 0; e < 4; ++e) {
      int ke = k + e, r = ke / I_, i = ke - r * I_;
      h[e] = f2bf(Wn[(size_t)r * (C_ * O_ * I_) + i]);
    }
    ushort4 o4; o4.x = h[0]; o4.y = h[1]; o4.z = h[2]; o4.w = h[3];
    *(ushort4*)&WtT[t] = o4;
  } else if (bid < 6000) {
    __shared__ u16 tile[64][72];
    int idx = bid - 5760;
    int kb = (idx % 60) << 6, bb = (idx / 60) << 6;
    int brow = threadIdx.x >> 4;          // 0..15
    int kq = (threadIdx.x & 15) << 2;     // 0..60 step 4
    #pragma unroll
    for (int p = 0; p < 4; ++p) {
      int bl = p * 16 + brow;
      float4 v = *(const float4*)(X + (size_t)(bb + bl) * K1 + kb + kq);
      ushort4 h;
      h.x = f2bf(v.x); h.y = f2bf(v.y); h.z = f2bf(v.z); h.w = f2bf(v.w);
      *(ushort4*)(Xk + (size_t)(bb + bl) * K1 + kb + kq) = h;
      tile[kq + 0][bl] = h.x;
      tile[kq + 1][bl] = h.y;
      tile[kq + 2][bl] = h.z;
      tile[kq + 3][bl] = h.w;
    }
    __syncthreads();
    int kr = threadIdx.x >> 3;            // 0..31
    int bq = (threadIdx.x & 7) << 3;      // 0..56 step 8
    #pragma unroll
    for (int q = 0; q < 2; ++q) {
      int kl = q * 32 + kr;
      *(uint4*)(xT + (size_t)(kb + kl) * B_ + bb + bq) = *(const uint4*)&tile[kl][bq];
    }
  } else {
    int t = ((bid - 6000) * 256 + threadIdx.x) << 2;  // bij: 18,432 floats
    if (t < R_ * C_) *(float4*)&bij[t] = (float4){0.f, 0.f, 0.f, 0.f};
  }
}

// scale 8 k-contiguous bf16 (global k = kg..kg+7) by softmax row(s)
__device__ inline uint4 scale_b8(uint4 raw, int kg, const float* smrow) {
  int r0 = kg / I_;
  int bnd = (r0 + 1) * I_ - kg;                // elements j<bnd use r0
  float s0 = smrow[r0];
  float s1 = smrow[(r0 + 1 < R_) ? r0 + 1 : R_ - 1];
  union { uint4 q; u16 h[8]; } u; u.q = raw;
  #pragma unroll
  for (int j = 0; j < 8; ++j)
    u.h[j] = f2bf(bf2f(u.h[j]) * ((j < bnd) ? s0 : s1));
  return u.q;
}

// ---- GEMM1 body (R5 verbatim): P^T[z][n][b] bf16, 128m x 64n tile,
// split-K z, 4 iters of BK64 (2 BK32 sub-tiles, ONE barrier each).
__device__ __forceinline__ void gemm1_body(
    Smem* S, int bx, int by, int bz,
    const u16* __restrict__ A, const u16* __restrict__ Bt,
    const float* __restrict__ bij, u16* __restrict__ P, int doScale) {
  int tid = threadIdx.x;
  int w = tid >> 6, lane = tid & 63;
  if (doScale) {  // wave-local softmax: wave w owns capsule (by<<2)+w
    int c = (by << 2) + w;
    float e0 = bij[c * R_ + lane];
    float e1 = bij[c * R_ + lane + 64];
    float e2 = bij[c * R_ + lane + 128];
    float mx = fmaxf(e0, fmaxf(e1, e2));
    #pragma unroll
    for (int off = 32; off > 0; off >>= 1) mx = fmaxf(mx, __shfl_xor(mx, off));
    e0 = expf(e0 - mx); e1 = expf(e1 - mx); e2 = expf(e2 - mx);
    float s = e0 + e1 + e2;
    #pragma unroll
    for (int off = 32; off > 0; off >>= 1) s += __shfl_xor(s, off);
    float inv = 1.0f / s;
    S->g1.sm[w][lane] = e0 * inv;
    S->g1.sm[w][lane + 64] = e1 * inv;
    S->g1.sm[w][lane + 128] = e2 * inv;
  }

  long m0 = (long)bx * 128, n0 = (long)by * 64;
  int k0 = bz * KCH;
  const u16* Ab = A + m0 * K1 + k0;
  const u16* Bb = Bt + n0 * K1 + k0;
  int q_s = ((lane & 3) - ((lane >> 3) & 3)) & 3;
  const u16* AgC[4]; int AlC[4];
  #pragma unroll
  for (int m = 0; m < 4; ++m) {
    AgC[m] = Ab + (long)(((m & 1) << 6) + (w << 4) + (lane >> 2)) * K1
             + ((m >> 1) << 5) + (q_s << 3);
    AlC[m] = (m << 11) + (w << 9);
  }
  const u16* BgC[2]; int BlC[2];
  #pragma unroll
  for (int m = 0; m < 2; ++m) {
    BgC[m] = Bb + (long)((w << 4) + (lane >> 2)) * K1 + (m << 5) + (q_s << 3);
    BlC[m] = (m << 11) + (w << 9);
  }
  int rowD = tid >> 2;
  int qD = ((tid & 3) - ((tid >> 3) & 3)) & 3;
  const u16* Bgs = Bb + (long)rowD * K1 + (qD << 3);
  const float* smrow = &S->g1.sm[w][0];   // capsule of row rowD = rowD>>4 = w
  int wm = (w >> 1) << 6, wn = (w & 1) << 5;
  int quad = lane >> 4, lrow = lane & 15;
  int swz = ((quad + (lrow >> 1)) & 3) << 3;   // frag-read sigma slot
  floatx4 acc[4][2];
  #pragma unroll
  for (int a = 0; a < 4; ++a)
    #pragma unroll
    for (int b = 0; b < 2; ++b) acc[a][b] = (floatx4){0.f, 0.f, 0.f, 0.f};

  #pragma unroll
  for (int m = 0; m < 4; ++m) async16(AgC[m], &S->g1.As[0][AlC[m]]);
  uint4 b0, b1;
  if (doScale) {
    b0 = *(const uint4*)Bgs;
    b1 = *(const uint4*)(Bgs + 32);
  } else {
    async16(BgC[0], &S->g1.Bs[0][BlC[0]]);
    async16(BgC[1], &S->g1.Bs[0][BlC[1]]);
  }
  __syncthreads();                   // asyncs drained; sm visible

  int p = 0;
  for (int kt = 0; kt < 4; ++kt) {
    if (doScale) {
      int kg = k0 + (kt << 6) + (qD << 3);
      *(uint4*)&S->g1.Bs[p][tid << 3] = scale_b8(b0, kg, smrow);
      *(uint4*)&S->g1.Bs[p][2048 + (tid << 3)] = scale_b8(b1, kg + 32, smrow);
      __syncthreads();               // Bs[p] visible; As[p] asyncs complete
    } else if (kt > 0) {
      __syncthreads();               // buf p asyncs complete
    }
    if (kt + 1 < 4) {                // prefetch escapes the barrier drain
      int kk = (kt + 1) << 6;
      #pragma unroll
      for (int m = 0; m < 4; ++m) async16(AgC[m] + kk, &S->g1.As[p ^ 1][AlC[m]]);
      if (doScale) {
        b0 = *(const uint4*)(Bgs + kk);
        b1 = *(const uint4*)(Bgs + kk + 32);
      } else {
        async16(BgC[0] + kk, &S->g1.Bs[p ^ 1][BlC[0]]);
        async16(BgC[1] + kk, &S->g1.Bs[p ^ 1][BlC[1]]);
      }
    }
    #pragma unroll
    for (int s = 0; s < 2; ++s) {
      short8 af[4], bfr[2];
      #pragma unroll
      for (int ms = 0; ms < 4; ++ms)
        af[ms] = *(const short8*)&S->g1.As[p][(s << 12)
                                        + ((wm + ms * 16 + lrow) << 5) + swz];
      #pragma unroll
      for (int ns = 0; ns < 2; ++ns)
        bfr[ns] = *(const short8*)&S->g1.Bs[p][(s << 11)
                                         + ((wn + ns * 16 + lrow) << 5) + swz];
      #pragma unroll
      for (int ms = 0; ms < 4; ++ms)
        #pragma unroll
        for (int ns = 0; ns < 2; ++ns)
          acc[ms][ns] = __builtin_amdgcn_mfma_f32_16x16x32_bf16(
              af[ms], bfr[ns], acc[ms][ns], 0, 0, 0);
    }
    p ^= 1;
  }
  size_t zb = (size_t)bz * (size_t)STILE;
  #pragma unroll
  for (int ms = 0; ms < 4; ++ms)
    #pragma unroll
    for (int ns = 0; ns < 2; ++ns) {
      int b = (int)m0 + wm + ms * 16 + (quad << 2);
      int n = (int)n0 + wn + ns * 16 + lrow;
      uint2 pk;
      pk.x = pack2(acc[ms][ns][0], acc[ms][ns][1]);
      pk.y = pack2(acc[ms][ns][2], acc[ms][ns][3]);
      *(uint2*)&P[zb + (size_t)n * B_ + b] = pk;
    }
}

// ---- redsq body (R0/R5 verbatim): grid (96 c, 4 bh); split-K reduce +
// squash -> vT/out.
__device__ __forceinline__ void redsq_body(
    Smem* S, int c, int bh, const u16* __restrict__ P,
    float* __restrict__ out, u16* __restrict__ vT, float preScale, int last) {
  int lane = threadIdx.x & 63, og = threadIdx.x >> 6;
  int b = (bh << 6) + lane;
  int n0 = (c << 4) + (og << 2);
  float acc[4];
  #pragma unroll
  for (int oo = 0; oo < 4; ++oo) acc[oo] = 0.f;
  #pragma unroll
  for (int z = 0; z < ZSPLIT; ++z) {
    size_t base = (size_t)z * STILE + (size_t)n0 * B_ + b;
    #pragma unroll
    for (int oo = 0; oo < 4; ++oo)
      acc[oo] += bf2f(P[base + (size_t)oo * B_]);
  }
  #pragma unroll
  for (int oo = 0; oo < 4; ++oo) acc[oo] *= preScale;
  float q = acc[0] * acc[0] + acc[1] * acc[1] + acc[2] * acc[2] + acc[3] * acc[3];
  S->rs.nsq_l[og][lane] = q;
  __syncthreads();
  float nsq = S->rs.nsq_l[0][lane] + S->rs.nsq_l[1][lane]
            + S->rs.nsq_l[2][lane] + S->rs.nsq_l[3][lane];
  float f = nsq / ((1.0f + nsq) * sqrtf(nsq));
  #pragma unroll
  for (int oo = 0; oo < 4; ++oo) acc[oo] *= f;
  if (last) {
    *(float4*)(out + (size_t)b * N_ + n0) = (float4){acc[0], acc[1], acc[2], acc[3]};
  } else {
    #pragma unroll
    for (int oo = 0; oo < 4; ++oo)
      vT[(size_t)(n0 + oo) * B_ + b] = f2bf(acc[oo]);
  }
}

// ---- GEMM2 + agreement body (R5 verbatim): 128m x 64n, (30,24) tiles.
__device__ __forceinline__ void gemm2_body(
    Smem* S, int bx, int by,
    const u16* __restrict__ A, const u16* __restrict__ Bt,
    const u16* __restrict__ WtT, float* __restrict__ bij) {
  const int K = 256;
  int tid = threadIdx.x;
  long m0 = (long)bx * 128, n0 = (long)by * 64;
  const u16* Ab = A + m0 * K;
  const u16* Bb = Bt + n0 * K;
  int w = tid >> 6, lane = tid & 63;
  int wm = (w >> 1) << 6, wn = (w & 1) << 5;
  int quad = lane >> 4, lrow = lane & 15;
  int swz = ((quad + (lrow >> 1)) & 3) << 3;
  int q_s = ((lane & 3) - ((lane >> 3) & 3)) & 3;
  const u16* AgC[4]; int AlC[4];
  #pragma unroll
  for (int m = 0; m < 4; ++m) {
    AgC[m] = Ab + (long)(((m & 1) << 6) + (w << 4) + (lane >> 2)) * K
             + ((m >> 1) << 5) + (q_s << 3);
    AlC[m] = (m << 11) + (w << 9);
  }
  const u16* BgC[2]; int BlC[2];
  #pragma unroll
  for (int m = 0; m < 2; ++m) {
    BgC[m] = Bb + (long)((w << 4) + (lane >> 2)) * K + (m << 5) + (q_s << 3);
    BlC[m] = (m << 11) + (w << 9);
  }
  floatx4 acc[4][2];
  #pragma unroll
  for (int a = 0; a < 4; ++a)
    #pragma unroll
    for (int b = 0; b < 2; ++b) acc[a][b] = (floatx4){0.f, 0.f, 0.f, 0.f};

  #pragma unroll
  for (int m = 0; m < 4; ++m) async16(AgC[m], &S->g2.As[0][AlC[m]]);
  async16(BgC[0], &S->g2.Bs[0][BlC[0]]);
  async16(BgC[1], &S->g2.Bs[0][BlC[1]]);

  int p = 0;
  #pragma unroll
  for (int kt = 0; kt < 4; ++kt) {
    __syncthreads();                 // buf p asyncs complete
    if (kt + 1 < 4) {
      int kk = (kt + 1) << 6;
      #pragma unroll
      for (int m = 0; m < 4; ++m) async16(AgC[m] + kk, &S->g2.As[p ^ 1][AlC[m]]);
      async16(BgC[0] + kk, &S->g2.Bs[p ^ 1][BlC[0]]);
      async16(BgC[1] + kk, &S->g2.Bs[p ^ 1][BlC[1]]);
    }
    #pragma unroll
    for (int s = 0; s < 2; ++s) {
      short8 af[4], bfr[2];
      #pragma unroll
      for (int ms = 0; ms < 4; ++ms)
        af[ms] = *(const short8*)&S->g2.As[p][(s << 12)
                                        + ((wm + ms * 16 + lrow) << 5) + swz];
      #pragma unroll
      for (int ns = 0; ns < 2; ++ns)
        bfr[ns] = *(const short8*)&S->g2.Bs[p][(s << 11)
                                         + ((wn + ns * 16 + lrow) << 5) + swz];
      #pragma unroll
      for (int ms = 0; ms < 4; ++ms)
        #pragma unroll
        for (int ns = 0; ns < 2; ++ns)
          acc[ms][ns] = __builtin_amdgcn_mfma_f32_16x16x32_bf16(
              af[ms], bfr[ns], acc[ms][ns], 0, 0, 0);
    }
    p ^= 1;
  }
  #pragma unroll
  for (int ms = 0; ms < 4; ++ms) {
    int rowbase = (int)m0 + wm + ms * 16;          // wave-uniform
    int r_lo = rowbase / I_;
    int r_hi = (rowbase + 15) / I_;
    int bnd = (r_lo + 1) * I_;
    int rowl = rowbase + (quad << 2);
    #pragma unroll
    for (int ns = 0; ns < 2; ++ns) {
      int col = (int)n0 + wn + ns * 16 + lrow;
      uint2 wv = *(const uint2*)&WtT[(size_t)col * K1 + rowl];
      u16 h[4];
      h[0] = (u16)(wv.x & 0xffff); h[1] = (u16)(wv.x >> 16);
      h[2] = (u16)(wv.y & 0xffff); h[3] = (u16)(wv.y >> 16);
      float p0 = 0.f, p1 = 0.f;
      #pragma unroll
      for (int e = 0; e < 4; ++e) {
        float pr = acc[ms][ns][e] * bf2f(h[e]);
        if (rowl + e < bnd) p0 += pr; else p1 += pr;
      }
      #pragma unroll
      for (int off = 32; off > 0; off >>= 1) {
        p0 += __shfl_xor(p0, off);
        p1 += __shfl_xor(p1, off);
      }
      if (lane == 0) {
        int c = col >> 4;
        atomicAdd(&bij[c * R_ + r_lo], p0 * (1.0f / 256.0f));
        atomicAdd(&bij[c * R_ + r_hi], p1 * (1.0f / 256.0f));
      }
    }
  }
}

// ---- classic standalone kernels (fallback path)
__global__ __launch_bounds__(256) void gemm1(
    const u16* __restrict__ A, const u16* __restrict__ Bt,
    const float* __restrict__ bij, u16* __restrict__ P, int doScale) {
  __shared__ Smem sh;
  gemm1_body(&sh, blockIdx.x, blockIdx.y, blockIdx.z, A, Bt, bij, P, doScale);
}
__global__ void k_redsq(const u16* __restrict__ P, float* __restrict__ out,
                        u16* __restrict__ vT, float preScale, int last) {
  __shared__ Smem sh;
  redsq_body(&sh, blockIdx.x, blockIdx.y, P, out, vT, preScale, last);
}
__global__ __launch_bounds__(256) void gemm2_agree(
    const u16* __restrict__ A, const u16* __restrict__ Bt,
    const u16* __restrict__ WtT, float* __restrict__ bij) {
  __shared__ Smem sh;
  gemm2_body(&sh, blockIdx.x, blockIdx.y, A, Bt, WtT, bij);
}

// ---- cooperative fused routing: grid 720 x 256, 7 grid syncs.
// Tile maps: gemm1 (2,24,15): x=bid&1, y=(bid>>1)%24, z=bid/48.
// redsq (96,4): c=bid%96, bh=bid/96 (bid<384; others idle at sync).
// gemm2 (30,24): x=bid%30, y=bid/30.
__global__ __launch_bounds__(256, 3) void routing_coop(
    const u16* __restrict__ Xk, const u16* __restrict__ WtT,
    const u16* __restrict__ xT, u16* __restrict__ vT, u16* __restrict__ Pb,
    float* __restrict__ bij, float* __restrict__ out) {
  __shared__ Smem sh;
  cg::grid_group grid = cg::this_grid();
  int bid = (int)blockIdx.x;
  #pragma unroll 1
  for (int it = 0; it < 3; ++it) {
    {
      int bz = bid / 48, rem = bid - bz * 48;
      gemm1_body(&sh, rem & 1, rem >> 1, bz, Xk, WtT, bij, Pb, it > 0);
    }
    grid.sync();                       // P visible grid-wide
    if (bid < 384)
      redsq_body(&sh, bid % 96, bid / 96, Pb, out, vT,
                 it == 0 ? (1.0f / 192.0f) : 1.0f, it == 2);
    if (it == 2) break;                // out written; done
    grid.sync();                       // vT visible
    gemm2_body(&sh, bid % 30, bid / 30, xT, vT, WtT, bij);
    grid.sync();                       // bij atomics visible
  }
}

extern "C" void kernel_launch(void* const* d_in, const int* in_sizes, int n_in,
                              void* d_out, int out_size, void* d_ws, size_t ws_size,
                              hipStream_t stream) {
  const float* X = (const float*)d_in[0];   // fp32 [256,192,20]
  const float* W = (const float*)d_in[1];   // fp32 [192,96,16,20]
  float* out = (float*)d_out;               // fp32 [256,96,16]
  char* ws = (char*)d_ws;
  u16*  WtT = (u16*)(ws);                   // 11,796,480 B
  u16*  Xk  = (u16*)(ws + 11796480);        //  1,966,080 B
  u16*  xT  = (u16*)(ws + 13762560);        //  1,966,080 B
  u16*  vT  = (u16*)(ws + 15728640);        //    786,432 B
  u16*  Pb  = (u16*)(ws + 16515072);        // 15 z x 786,432 B = 11,796,480 B
  float* bij = (float*)(ws + 28311552);     //     73,728 B (c-major [c][r])

  k_prep<<<6018, 256, 0, stream>>>(W, X, WtT, Xk, xT, bij);

  void* kargs[] = {(void*)&Xk, (void*)&WtT, (void*)&xT, (void*)&vT,
                   (void*)&Pb, (void*)&bij, (void*)&out};
  hipError_t ce = hipLaunchCooperativeKernel(
      (void*)routing_coop, dim3(720), dim3(256), kargs, 0, stream);
  if (ce != hipSuccess) {
    // fallback: classic 9-dispatch R5 path (bit-identical math)
    for (int it = 0; it < 3; ++it) {
      gemm1<<<dim3(2, 24, ZSPLIT), 256, 0, stream>>>(Xk, WtT, bij, Pb, it > 0);
      k_redsq<<<dim3(96, 4), 256, 0, stream>>>(
          Pb, out, vT, it == 0 ? (1.0f / 192.0f) : 1.0f, it == 2);
      if (it < 2)
        gemm2_agree<<<dim3(30, 24), 256, 0, stream>>>(xT, vT, WtT, bij);
    }
  }
}

// Round 8
// 147.400 us; speedup vs baseline: 6.0858x; 6.0858x over previous
//
#include <hip/hip_runtime.h>

// DigitCaps dynamic routing, B=256 R=192 C=96 O=16 I=20. fp32 in/out.
// u_hat never materialized. 9 dispatches (R0/R5 proven structure):
//   prep: W->WtT bf16 k-major (R8: coalesced-READ gather, scattered 8B
//     writes absorbed by L2; was 80B-row gathers = 1.6x HBM overfetch);
//     X->Xk + xT; bij=0 (c-major)
//   gemm1 (x3): 128m x 64n tile, split-K=15, 1-D grid 720 with XCD-aware
//     decode (R8: y=g*3+s%3, z=(s/3)%15, x=s/45; each XCD owns 3 n-slices
//     -> every WtT B-tile in exactly one L2); A async global_load_lds(16B);
//     B: it0 async, else reg-prefetch + wave-local softmax scale at
//     LDS-write; double LDS; sigma-swz (R5); partials bf16 P^T[z][n][b]
//   redsq (x3): grid (96,4); split-K reduce (+preScale) + squash -> vT/out
//   gemm2_agree (x2): 128x64 tile, 1-D grid 720 XCD-decoded (y=g*3+s%3,
//     x=s/3: vT B-tiles x1 L2 instead of x8); agreement epilogue, atomicAdd
// Lessons: R1 __threadfence + R7 grid.sync = XCD coherence storm (>=100us
//   per coherence point; dispatch boundary IS the cheap global barrier).
//   R2/R3 full-K small tile = 2x traffic, BW-bound, pipelining null.
//   R4 staging chunk order must keep 4-consecutive-chunks = one row.
//   R5 sigma-swz neutral (kept, free). R6 redsq/gemm2 rewrites regressed.

#define R_ 192
#define C_ 96
#define O_ 16
#define I_ 20
#define B_ 256
#define K1 3840   // R*I
#define N_ 1536   // C*O
#define ZSPLIT 15
#define KCH 256       // K1/ZSPLIT; 4 iters of BK=64 (2x BK32 sub-tiles)
#define STILE 393216  // N_*B_ elements per z-slice

typedef unsigned short u16;
typedef __attribute__((ext_vector_type(8))) short short8;
typedef __attribute__((ext_vector_type(4))) float floatx4;

__device__ inline float bf2f(u16 h) {
  union { unsigned int u; float f; } x; x.u = ((unsigned int)h) << 16; return x.f;
}
__device__ inline u16 f2bf(float f) {
  union { float f; unsigned int u; } x; x.f = f;
  unsigned int r = x.u + 0x7FFFu + ((x.u >> 16) & 1u);
  return (u16)(r >> 16);
}
__device__ inline unsigned int pack2(float a, float b) {
  return (unsigned int)f2bf(a) | ((unsigned int)f2bf(b) << 16);
}
// async 16B/lane global->LDS; lds base wave-uniform (lane scatters +16B)
__device__ inline void async16(const u16* g, u16* l) {
  __builtin_amdgcn_global_load_lds(
      (__attribute__((address_space(1))) void*)(unsigned long long)g,
      (__attribute__((address_space(3))) void*)(unsigned int)(unsigned long long)l,
      16, 0, 0);
}

// ---- fused prep: WtT gather (5760 blocks: r=bid/30, coalesced float4
// reads of W, scattered 8B WtT writes -> L2-absorbed); X cast+transpose
// (240); bij=0 c-major (18)
__global__ void k_prep(const float* __restrict__ W, const float* __restrict__ X,
                       u16* __restrict__ WtT, u16* __restrict__ Xk,
                       u16* __restrict__ xT, float* __restrict__ bij) {
  int bid = blockIdx.x;
  if (bid < 5760) {
    int r = bid / 30, xb = bid - r * 30;
    int j4 = (xb << 10) + ((int)threadIdx.x << 2);   // 0..30716, step 4
    // j4 = c*320 + o*20 + i; i in {0,4,8,12,16} (20=5*4: never straddles o)
    int c = j4 / 320, rem = j4 - c * 320;
    int o = rem / 20, i = rem - o * 20;
    float4 v = *(const float4*)(W + (size_t)r * (C_ * O_ * I_) + j4);
    ushort4 h;
    h.x = f2bf(v.x); h.y = f2bf(v.y); h.z = f2bf(v.z); h.w = f2bf(v.w);
    *(ushort4*)&WtT[(size_t)(c * O_ + o) * K1 + r * I_ + i] = h;
  } else if (bid < 6000) {
    __shared__ u16 tile[64][72];
    int idx = bid - 5760;
    int kb = (idx % 60) << 6, bb = (idx / 60) << 6;
    int brow = threadIdx.x >> 4;          // 0..15
    int kq = (threadIdx.x & 15) << 2;     // 0..60 step 4
    #pragma unroll
    for (int p = 0; p < 4; ++p) {
      int bl = p * 16 + brow;
      float4 v = *(const float4*)(X + (size_t)(bb + bl) * K1 + kb + kq);
      ushort4 h;
      h.x = f2bf(v.x); h.y = f2bf(v.y); h.z = f2bf(v.z); h.w = f2bf(v.w);
      *(ushort4*)(Xk + (size_t)(bb + bl) * K1 + kb + kq) = h;
      tile[kq + 0][bl] = h.x;
      tile[kq + 1][bl] = h.y;
      tile[kq + 2][bl] = h.z;
      tile[kq + 3][bl] = h.w;
    }
    __syncthreads();
    int kr = threadIdx.x >> 3;            // 0..31
    int bq = (threadIdx.x & 7) << 3;      // 0..56 step 8
    #pragma unroll
    for (int q = 0; q < 2; ++q) {
      int kl = q * 32 + kr;
      *(uint4*)(xT + (size_t)(kb + kl) * B_ + bb + bq) = *(const uint4*)&tile[kl][bq];
    }
  } else {
    int t = ((bid - 6000) * 256 + threadIdx.x) << 2;  // bij: 18,432 floats
    if (t < R_ * C_) *(float4*)&bij[t] = (float4){0.f, 0.f, 0.f, 0.f};
  }
}

// scale 8 k-contiguous bf16 (global k = kg..kg+7) by softmax row(s)
__device__ inline uint4 scale_b8(uint4 raw, int kg, const float* smrow) {
  int r0 = kg / I_;
  int bnd = (r0 + 1) * I_ - kg;                // elements j<bnd use r0
  float s0 = smrow[r0];
  float s1 = smrow[(r0 + 1 < R_) ? r0 + 1 : R_ - 1];
  union { uint4 q; u16 h[8]; } u; u.q = raw;
  #pragma unroll
  for (int j = 0; j < 8; ++j)
    u.h[j] = f2bf(bf2f(u.h[j]) * ((j < bnd) ? s0 : s1));
  return u.q;
}

// LDS sigma-swizzle layout (per buffer, per matrix):
//   elem(sub, row, q, j) -> sub*(rows*32) + row*32 + ((q+(row>>1))&3)*8 + j
// Chunk id gc = sub*(rows*4) + row*4 + sigma; staged LINEARLY at gc*16B.
// Inverse (for staging source): row = cc>>2, sigma = cc&3,
//   q = (sigma - ((row>>1)&3)) & 3. Per 4 consecutive chunks: one row,
//   4 k-groups permuted inside one 64B global segment (full coalescing).

// ---- GEMM1: P^T[z][n][b] bf16 = (Xk[256,3840] x (c*WtT)[1536,3840]^T),
// k-chunk z (256 = 4 x BK64; each BK64 = 2 BK32 sub-tiles, ONE barrier).
// 128m x 64n tile, 4 waves of 64x32. 1-D grid 720, XCD-aware decode:
// g=bid&7 (XCD), y=g*3+s%3, z=(s/3)%15, x=s/45 -> each XCD owns 3
// n-slices x all z: B-tiles single-L2.
__global__ __launch_bounds__(256) void gemm1(
    const u16* __restrict__ A, const u16* __restrict__ Bt,
    const float* __restrict__ bij, u16* __restrict__ P, int doScale) {
  __shared__ u16 As[2][8192];   // 32 KB (sigma-swz)
  __shared__ u16 Bs[2][4096];   // 16 KB (sigma-swz)
  __shared__ float sm[4][192];
  int bid = (int)blockIdx.x;
  int g = bid & 7, s5 = bid >> 3;
  int by = g * 3 + s5 % 3;
  int s3 = s5 / 3;
  int bz = s3 % 15, bx = s3 / 15;
  int tid = threadIdx.x;
  int w = tid >> 6, lane = tid & 63;
  if (doScale) {  // wave-local softmax: wave w owns capsule (by<<2)+w
    int c = (by << 2) + w;
    float e0 = bij[c * R_ + lane];
    float e1 = bij[c * R_ + lane + 64];
    float e2 = bij[c * R_ + lane + 128];
    float mx = fmaxf(e0, fmaxf(e1, e2));
    #pragma unroll
    for (int off = 32; off > 0; off >>= 1) mx = fmaxf(mx, __shfl_xor(mx, off));
    e0 = expf(e0 - mx); e1 = expf(e1 - mx); e2 = expf(e2 - mx);
    float s = e0 + e1 + e2;
    #pragma unroll
    for (int off = 32; off > 0; off >>= 1) s += __shfl_xor(s, off);
    float inv = 1.0f / s;
    sm[w][lane] = e0 * inv;
    sm[w][lane + 64] = e1 * inv;
    sm[w][lane + 128] = e2 * inv;
  }

  long m0 = (long)bx * 128, n0 = (long)by * 64;
  int k0 = bz * KCH;
  const u16* Ab = A + m0 * K1 + k0;
  const u16* Bb = Bt + n0 * K1 + k0;
  // staging source permutation (wave-call covers 64 consecutive chunks):
  // lane l -> row_off = l>>2, k-group q_s = ((l&3) - ((l>>3)&3)) & 3.
  int q_s = ((lane & 3) - ((lane >> 3) & 3)) & 3;
  // A: call m (0..3): row = ((m&1)<<6) + (w<<4) + (l>>2);
  //    col = (m>>1)*32 + q_s*8; LDS base elem = (m<<11)+(w<<9).
  const u16* AgC[4]; int AlC[4];
  #pragma unroll
  for (int m = 0; m < 4; ++m) {
    AgC[m] = Ab + (long)(((m & 1) << 6) + (w << 4) + (lane >> 2)) * K1
             + ((m >> 1) << 5) + (q_s << 3);
    AlC[m] = (m << 11) + (w << 9);
  }
  // B async (it0): call m (0..1): row = (w<<4)+(l>>2); col = m*32 + q_s*8.
  const u16* BgC[2]; int BlC[2];
  #pragma unroll
  for (int m = 0; m < 2; ++m) {
    BgC[m] = Bb + (long)((w << 4) + (lane >> 2)) * K1 + (m << 5) + (q_s << 3);
    BlC[m] = (m << 11) + (w << 9);
  }
  // doScale reg-staging: thread tid -> chunk tid of sub0 (+ sub1 at +2048):
  // row = tid>>2, qD = ((tid&3) - ((tid>>3)&3)) & 3; write = linear 16B.
  int rowD = tid >> 2;
  int qD = ((tid & 3) - ((tid >> 3) & 3)) & 3;
  const u16* Bgs = Bb + (long)rowD * K1 + (qD << 3);
  const float* smrow = &sm[w][0];         // capsule of row rowD = rowD>>4 = w
  int wm = (w >> 1) << 6, wn = (w & 1) << 5;
  int quad = lane >> 4, lrow = lane & 15;
  int swz = ((quad + (lrow >> 1)) & 3) << 3;   // frag-read sigma slot
  floatx4 acc[4][2];
  #pragma unroll
  for (int a = 0; a < 4; ++a)
    #pragma unroll
    for (int b = 0; b < 2; ++b) acc[a][b] = (floatx4){0.f, 0.f, 0.f, 0.f};

  // kt=0 staging: both sub-tiles
  #pragma unroll
  for (int m = 0; m < 4; ++m) async16(AgC[m], &As[0][AlC[m]]);
  uint4 b0, b1;
  if (doScale) {
    b0 = *(const uint4*)Bgs;
    b1 = *(const uint4*)(Bgs + 32);
  } else {
    async16(BgC[0], &Bs[0][BlC[0]]);
    async16(BgC[1], &Bs[0][BlC[1]]);
  }
  __syncthreads();                   // asyncs drained; sm visible

  int p = 0;
  for (int kt = 0; kt < 4; ++kt) {
    if (doScale) {                   // thread's B k-cols: qD*8 (+32 sub1)
      int kg = k0 + (kt << 6) + (qD << 3);
      *(uint4*)&Bs[p][tid << 3] = scale_b8(b0, kg, smrow);
      *(uint4*)&Bs[p][2048 + (tid << 3)] = scale_b8(b1, kg + 32, smrow);
      __syncthreads();               // Bs[p] visible; As[p] asyncs complete
    } else if (kt > 0) {
      __syncthreads();               // buf p asyncs complete
    }
    if (kt + 1 < 4) {                // prefetch escapes the barrier drain
      int kk = (kt + 1) << 6;
      #pragma unroll
      for (int m = 0; m < 4; ++m) async16(AgC[m] + kk, &As[p ^ 1][AlC[m]]);
      if (doScale) {
        b0 = *(const uint4*)(Bgs + kk);
        b1 = *(const uint4*)(Bgs + kk + 32);
      } else {
        async16(BgC[0] + kk, &Bs[p ^ 1][BlC[0]]);
        async16(BgC[1] + kk, &Bs[p ^ 1][BlC[1]]);
      }
    }
    #pragma unroll
    for (int s = 0; s < 2; ++s) {
      short8 af[4], bfr[2];
      #pragma unroll
      for (int ms = 0; ms < 4; ++ms)
        af[ms] = *(const short8*)&As[p][(s << 12)
                                        + ((wm + ms * 16 + lrow) << 5) + swz];
      #pragma unroll
      for (int ns = 0; ns < 2; ++ns)
        bfr[ns] = *(const short8*)&Bs[p][(s << 11)
                                         + ((wn + ns * 16 + lrow) << 5) + swz];
      #pragma unroll
      for (int ms = 0; ms < 4; ++ms)
        #pragma unroll
        for (int ns = 0; ns < 2; ++ns)
          acc[ms][ns] = __builtin_amdgcn_mfma_f32_16x16x32_bf16(
              af[ms], bfr[ns], acc[ms][ns], 0, 0, 0);
    }
    p ^= 1;
  }
  // transposed bf16 store: P[z][n*256 + b]; lane holds 4 consecutive b
  size_t zb = (size_t)bz * (size_t)STILE;
  #pragma unroll
  for (int ms = 0; ms < 4; ++ms)
    #pragma unroll
    for (int ns = 0; ns < 2; ++ns) {
      int b = (int)m0 + wm + ms * 16 + (quad << 2);
      int n = (int)n0 + wn + ns * 16 + lrow;
      uint2 pk;
      pk.x = pack2(acc[ms][ns][0], acc[ms][ns][1]);
      pk.y = pack2(acc[ms][ns][2], acc[ms][ns][3]);
      *(uint2*)&P[zb + (size_t)n * B_ + b] = pk;
    }
}

// ---- fused split-K reduce + squash, reading P^T[z][n][b] bf16.
// grid (96 c, 4 b-quarters); block 256 = 4 o-groups x 64 lanes; 1 b/lane.
__global__ void k_redsq(const u16* __restrict__ P, float* __restrict__ out,
                        u16* __restrict__ vT, float preScale, int last) {
  __shared__ float nsq_l[4][64];
  int c = blockIdx.x, bh = blockIdx.y;
  int lane = threadIdx.x & 63, og = threadIdx.x >> 6;
  int b = (bh << 6) + lane;
  int n0 = (c << 4) + (og << 2);
  float acc[4];
  #pragma unroll
  for (int oo = 0; oo < 4; ++oo) acc[oo] = 0.f;
  #pragma unroll
  for (int z = 0; z < ZSPLIT; ++z) {
    size_t base = (size_t)z * STILE + (size_t)n0 * B_ + b;
    #pragma unroll
    for (int oo = 0; oo < 4; ++oo)
      acc[oo] += bf2f(P[base + (size_t)oo * B_]);
  }
  #pragma unroll
  for (int oo = 0; oo < 4; ++oo) acc[oo] *= preScale;
  float q = acc[0] * acc[0] + acc[1] * acc[1] + acc[2] * acc[2] + acc[3] * acc[3];
  nsq_l[og][lane] = q;
  __syncthreads();
  float nsq = nsq_l[0][lane] + nsq_l[1][lane] + nsq_l[2][lane] + nsq_l[3][lane];
  float f = nsq / ((1.0f + nsq) * sqrtf(nsq));
  #pragma unroll
  for (int oo = 0; oo < 4; ++oo) acc[oo] *= f;
  if (last) {
    *(float4*)(out + (size_t)b * N_ + n0) = (float4){acc[0], acc[1], acc[2], acc[3]};
  } else {
    #pragma unroll
    for (int oo = 0; oo < 4; ++oo)
      vT[(size_t)(n0 + oo) * B_ + b] = f2bf(acc[oo]);
  }
}

// ---- GEMM2 + agreement fused, 128m x 64n tile, K=256 = 4 x BK64
// (2 BK32 sub-tiles per barrier), fully async staging; sigma-swz.
// 1-D grid 720, XCD decode: y=g*3+s%3, x=s/3 -> vT B-tiles single-L2.
__global__ __launch_bounds__(256) void gemm2_agree(
    const u16* __restrict__ A, const u16* __restrict__ Bt,
    const u16* __restrict__ WtT, float* __restrict__ bij) {
  const int K = 256;
  __shared__ u16 As[2][8192];
  __shared__ u16 Bs[2][4096];
  int bid = (int)blockIdx.x;
  int g = bid & 7, s5 = bid >> 3;
  int by = g * 3 + s5 % 3;
  int bx = s5 / 3;                   // 0..29
  int tid = threadIdx.x;
  long m0 = (long)bx * 128, n0 = (long)by * 64;
  const u16* Ab = A + m0 * K;
  const u16* Bb = Bt + n0 * K;
  int w = tid >> 6, lane = tid & 63;
  int wm = (w >> 1) << 6, wn = (w & 1) << 5;
  int quad = lane >> 4, lrow = lane & 15;
  int swz = ((quad + (lrow >> 1)) & 3) << 3;
  int q_s = ((lane & 3) - ((lane >> 3) & 3)) & 3;
  const u16* AgC[4]; int AlC[4];
  #pragma unroll
  for (int m = 0; m < 4; ++m) {
    AgC[m] = Ab + (long)(((m & 1) << 6) + (w << 4) + (lane >> 2)) * K
             + ((m >> 1) << 5) + (q_s << 3);
    AlC[m] = (m << 11) + (w << 9);
  }
  const u16* BgC[2]; int BlC[2];
  #pragma unroll
  for (int m = 0; m < 2; ++m) {
    BgC[m] = Bb + (long)((w << 4) + (lane >> 2)) * K + (m << 5) + (q_s << 3);
    BlC[m] = (m << 11) + (w << 9);
  }
  floatx4 acc[4][2];
  #pragma unroll
  for (int a = 0; a < 4; ++a)
    #pragma unroll
    for (int b = 0; b < 2; ++b) acc[a][b] = (floatx4){0.f, 0.f, 0.f, 0.f};

  #pragma unroll
  for (int m = 0; m < 4; ++m) async16(AgC[m], &As[0][AlC[m]]);
  async16(BgC[0], &Bs[0][BlC[0]]);
  async16(BgC[1], &Bs[0][BlC[1]]);

  int p = 0;
  #pragma unroll
  for (int kt = 0; kt < 4; ++kt) {
    __syncthreads();                 // buf p asyncs complete
    if (kt + 1 < 4) {                // async prefetch escapes the drain
      int kk = (kt + 1) << 6;
      #pragma unroll
      for (int m = 0; m < 4; ++m) async16(AgC[m] + kk, &As[p ^ 1][AlC[m]]);
      async16(BgC[0] + kk, &Bs[p ^ 1][BlC[0]]);
      async16(BgC[1] + kk, &Bs[p ^ 1][BlC[1]]);
    }
    #pragma unroll
    for (int s = 0; s < 2; ++s) {
      short8 af[4], bfr[2];
      #pragma unroll
      for (int ms = 0; ms < 4; ++ms)
        af[ms] = *(const short8*)&As[p][(s << 12)
                                        + ((wm + ms * 16 + lrow) << 5) + swz];
      #pragma unroll
      for (int ns = 0; ns < 2; ++ns)
        bfr[ns] = *(const short8*)&Bs[p][(s << 11)
                                         + ((wn + ns * 16 + lrow) << 5) + swz];
      #pragma unroll
      for (int ms = 0; ms < 4; ++ms)
        #pragma unroll
        for (int ns = 0; ns < 2; ++ns)
          acc[ms][ns] = __builtin_amdgcn_mfma_f32_16x16x32_bf16(
              af[ms], bfr[ns], acc[ms][ns], 0, 0, 0);
    }
    p ^= 1;
  }
  // epilogue: per fragment, cols = one capsule c; 16 rows span <=2 routes r.
  #pragma unroll
  for (int ms = 0; ms < 4; ++ms) {
    int rowbase = (int)m0 + wm + ms * 16;          // wave-uniform
    int r_lo = rowbase / I_;
    int r_hi = (rowbase + 15) / I_;
    int bnd = (r_lo + 1) * I_;
    int rowl = rowbase + (quad << 2);
    #pragma unroll
    for (int ns = 0; ns < 2; ++ns) {
      int col = (int)n0 + wn + ns * 16 + lrow;
      uint2 wv = *(const uint2*)&WtT[(size_t)col * K1 + rowl];
      u16 h[4];
      h[0] = (u16)(wv.x & 0xffff); h[1] = (u16)(wv.x >> 16);
      h[2] = (u16)(wv.y & 0xffff); h[3] = (u16)(wv.y >> 16);
      float p0 = 0.f, p1 = 0.f;
      #pragma unroll
      for (int e = 0; e < 4; ++e) {
        float pr = acc[ms][ns][e] * bf2f(h[e]);
        if (rowl + e < bnd) p0 += pr; else p1 += pr;
      }
      #pragma unroll
      for (int off = 32; off > 0; off >>= 1) {
        p0 += __shfl_xor(p0, off);
        p1 += __shfl_xor(p1, off);
      }
      if (lane == 0) {
        int c = col >> 4;
        atomicAdd(&bij[c * R_ + r_lo], p0 * (1.0f / 256.0f));
        atomicAdd(&bij[c * R_ + r_hi], p1 * (1.0f / 256.0f));
      }
    }
  }
}

extern "C" void kernel_launch(void* const* d_in, const int* in_sizes, int n_in,
                              void* d_out, int out_size, void* d_ws, size_t ws_size,
                              hipStream_t stream) {
  const float* X = (const float*)d_in[0];   // fp32 [256,192,20]
  const float* W = (const float*)d_in[1];   // fp32 [192,96,16,20]
  float* out = (float*)d_out;               // fp32 [256,96,16]
  char* ws = (char*)d_ws;
  u16*  WtT = (u16*)(ws);                   // 11,796,480 B
  u16*  Xk  = (u16*)(ws + 11796480);        //  1,966,080 B
  u16*  xT  = (u16*)(ws + 13762560);        //  1,966,080 B
  u16*  vT  = (u16*)(ws + 15728640);        //    786,432 B
  u16*  Pb  = (u16*)(ws + 16515072);        // 15 z x 786,432 B = 11,796,480 B
  float* bij = (float*)(ws + 28311552);     //     73,728 B (c-major [c][r])

  k_prep<<<6018, 256, 0, stream>>>(W, X, WtT, Xk, xT, bij);

  for (int it = 0; it < 3; ++it) {
    // s partials: M=256,N=1536,K=3840, grid 720 (XCD-decoded), 4 BK64 iters.
    // iter 0: no scale in gemm1; uniform softmax 1/192 applied in redsq.
    gemm1<<<720, 256, 0, stream>>>(Xk, WtT, bij, Pb, it > 0);
    k_redsq<<<dim3(96, 4), 256, 0, stream>>>(
        Pb, out, vT, it == 0 ? (1.0f / 192.0f) : 1.0f, it == 2);
    if (it < 2)
      gemm2_agree<<<720, 256, 0, stream>>>(xT, vT, WtT, bij);
  }
}